// Round 8
// baseline (658.102 us; speedup 1.0000x reference)
//
#include <hip/hip_runtime.h>

#define NB 64      // batch
#define SEQ 305    // sequence length
#define DIM 2048   // hidden
#define NP 256     // patches
#define NT 48      // task tokens
#define NKEEP 128  // kept patches
#define SOUT 177   // 1 + 128 + 48
#define KS 32      // d-depth per LDS stage (128 B per row)

static_assert(1 + NP + NT == SEQ, "layout");

constexpr float kScale = 0.022097086912079608f;  // 1/sqrt(2048)

// ---------------------------------------------------------------------------
// K1a: grid (1+ndc, 64). x==0: fused static copy of cls+task rows.
// Else: split-K partial GEMM, tile 256p x 48t x dchunk, micro-tile 8x6.
// 256 thr: pg=t>>3 (rows pg*8..+7), tg=t&7 (cols tg*6..+5).
// LDS [row][32] fp32 with XOR f4-slot swizzle:
//   write sl = c8 ^ ((row>>3)&7)  -> each 8-lane row-group hits 8 distinct
//     slots = all 32 banks, conflict-free b128 writes;
//   read slot for p rows pg*8+i: (j0 ^ (pg&7)) -> 8 distinct slots per wave
//     instruction, conflict-free; t reads ~2-way (free).
// Inner: per j0 (d-quartet), tv[6] then per-i transient pv + 24 FMAs
// (8x6x4 = 192 MACs per 14 b128 reads = 3.43 MAC/float, R5-validated ratio).
// ssq fused into staging regs, shfl-reduced (fixed order, deterministic).
// ---------------------------------------------------------------------------
__global__ __launch_bounds__(256) void k1a_partial_gemm(
    const float* __restrict__ tokens, float* __restrict__ rpart,
    float* __restrict__ ssqP, float* __restrict__ ssqT,
    float* __restrict__ out0, int ndc, int dchunk) {
  const int b = blockIdx.y;
  const int t = threadIdx.x;

  if (blockIdx.x == 0) {
    // copy cls (row 0 -> 0) and task rows (257..304 -> 129..176)
#pragma unroll 2
    for (int l = 0; l < 98; ++l) {
      int u = l * 256 + t;  // 49 rows * 512 f4
      int row = u >> 9, c = u & 511;
      int srow = (row == 0) ? 0 : (256 + row);
      int drow = (row == 0) ? 0 : (128 + row);
      *(float4*)(out0 + ((size_t)b * SOUT + drow) * DIM + (size_t)c * 4) =
          *(const float4*)(tokens + ((size_t)b * SEQ + srow) * DIM + (size_t)c * 4);
    }
    return;
  }

  const int dci = blockIdx.x - 1;  // 0..ndc-1
  const int pg = t >> 3;           // 0..31: p-rows pg*8..pg*8+7
  const int tg = t & 7;            // 0..7:  t-cols tg*6..tg*6+5

  __shared__ __align__(16) float pC[256][32];  // 32 KB
  __shared__ __align__(16) float tC[48][32];   // 6 KB

  const float* pbase = tokens + ((size_t)b * SEQ + 1) * DIM + (size_t)dci * dchunk;
  const float* tbase = tokens + ((size_t)b * SEQ + 1 + NP) * DIM + (size_t)dci * dchunk;

  float4 st[10];
  float acc[8][6] = {};
  float ssqa[10] = {};
  const int nchunk = dchunk / KS;

  // staging map: u = t + 256*l. u<2048: p (row=u>>3, c8=u&7);
  // 2048<=u<2432: t (v=u-2048: row=v>>3, c8=v&7). l=0..7 pure-p, l=8 pure-t,
  // l=9 t for t<128 (branches resolve per l at compile time).
  auto gload = [&](int ck) {
#pragma unroll
    for (int l = 0; l < 10; ++l) {
      int u = t + 256 * l;
      if (u < 2048) {
        int row = u >> 3, c8 = u & 7;
        st[l] = *(const float4*)(pbase + (size_t)row * DIM + ck * KS + c8 * 4);
      } else if (u < 2432) {
        int v = u - 2048;
        int row = v >> 3, c8 = v & 7;
        st[l] = *(const float4*)(tbase + (size_t)row * DIM + ck * KS + c8 * 4);
      }
    }
  };
  auto lwrite = [&]() {
#pragma unroll
    for (int l = 0; l < 10; ++l) {
      int u = t + 256 * l;
      float4 v = st[l];
      if (u < 2048) {
        int row = u >> 3, c8 = u & 7;
        int sl = c8 ^ ((row >> 3) & 7);
        *(float4*)&pC[row][sl * 4] = v;
        ssqa[l] += v.x * v.x + v.y * v.y + v.z * v.z + v.w * v.w;
      } else if (u < 2432) {
        int vv = u - 2048;
        int row = vv >> 3, c8 = vv & 7;
        int sl = c8 ^ ((row >> 3) & 7);
        *(float4*)&tC[row][sl * 4] = v;
        ssqa[l] += v.x * v.x + v.y * v.y + v.z * v.z + v.w * v.w;
      }
    }
  };

  gload(0);
  for (int ck = 0; ck < nchunk; ++ck) {
    __syncthreads();  // previous compute done reading LDS
    lwrite();
    if (ck + 1 < nchunk) gload(ck + 1);  // prefetch overlaps compute below
    __syncthreads();
#pragma unroll
    for (int j0 = 0; j0 < 8; ++j0) {
      float4 tv[6];
#pragma unroll
      for (int j = 0; j < 6; ++j) {
        int rt = tg * 6 + j;
        tv[j] = *(const float4*)&tC[rt][((j0 ^ (rt >> 3)) & 7) * 4];
      }
      const int psl = ((j0 ^ (pg & 7)) & 7) * 4;
#pragma unroll
      for (int i = 0; i < 8; ++i) {
        float4 pv = *(const float4*)&pC[pg * 8 + i][psl];
#pragma unroll
        for (int j = 0; j < 6; ++j)
          acc[i][j] += pv.x * tv[j].x + pv.y * tv[j].y + pv.z * tv[j].z +
                       pv.w * tv[j].w;
      }
    }
  }

  // partial R, transposed: rpart[(b*ndc+dci)][jg][256]
  float* rp = rpart + ((size_t)b * ndc + dci) * (NT * NP);
#pragma unroll
  for (int j = 0; j < 6; ++j) {
    int jg = tg * 6 + j;
    float4 v0 = {acc[0][j], acc[1][j], acc[2][j], acc[3][j]};
    float4 v1 = {acc[4][j], acc[5][j], acc[6][j], acc[7][j]};
    *(float4*)(rp + jg * NP + pg * 8) = v0;
    *(float4*)(rp + jg * NP + pg * 8 + 4) = v1;
  }

  // ssq: reduce across the 8 staging lanes of each row (fixed order)
#pragma unroll
  for (int l = 0; l < 10; ++l) {
    float s = ssqa[l];
    s += __shfl_down(s, 4, 8);
    s += __shfl_down(s, 2, 8);
    s += __shfl_down(s, 1, 8);
    ssqa[l] = s;
  }
  if ((t & 7) == 0) {
#pragma unroll
    for (int l = 0; l < 10; ++l) {
      int u = t + 256 * l;
      if (u < 2048) {
        ssqP[((size_t)b * ndc + dci) * NP + (u >> 3)] = ssqa[l];
      } else if (u < 2432) {
        ssqT[((size_t)b * ndc + dci) * NT + ((u - 2048) >> 3)] = ssqa[l];
      }
    }
  }
}

// ---------------------------------------------------------------------------
// K1b: grid (4 pt, 64 b), 256 thr. Sum ndc partials in fixed order
// (deterministic), rms + softmax, write attnp = softmax*invT and
// rn = raw*invP. Inits umax.
// ---------------------------------------------------------------------------
__global__ __launch_bounds__(256) void k1b_reduce_softmax(
    const float* __restrict__ rpart, const float* __restrict__ ssqP,
    const float* __restrict__ ssqT, float* __restrict__ attnp,
    float* __restrict__ rn, unsigned long long* __restrict__ umax, int ndc) {
  const int pt = blockIdx.x;
  const int b = blockIdx.y;
  const int t = threadIdx.x;
  const int r = t & 63;
  const int q = t >> 6;

  __shared__ float L[64][49];
  __shared__ float invPs[64];
  __shared__ float invTs[48];

  float a[12] = {};
  const float* rb = rpart + (size_t)b * ndc * (NT * NP) + pt * 64 + r;
  for (int dci = 0; dci < ndc; ++dci) {
    const float* rp = rb + (size_t)dci * (NT * NP);
#pragma unroll
    for (int j = 0; j < 12; ++j) a[j] += rp[(q * 12 + j) * NP];
  }
#pragma unroll
  for (int j = 0; j < 12; ++j) L[r][q * 12 + j] = a[j];

  if (t < 64) {
    float s = 0.f;
    for (int dci = 0; dci < ndc; ++dci)
      s += ssqP[((size_t)b * ndc + dci) * NP + pt * 64 + t];
    invPs[t] = 1.0f / sqrtf(s * (1.0f / 2048.0f) + 1e-6f);
    umax[(size_t)b * NP + pt * 64 + t] = 0ull;
  } else if (t < 112) {
    int j = t - 64;
    float s = 0.f;
    for (int dci = 0; dci < ndc; ++dci)
      s += ssqT[((size_t)b * ndc + dci) * NT + j];
    invTs[j] = 1.0f / sqrtf(s * (1.0f / 2048.0f) + 1e-6f);
  }
  __syncthreads();

  if (t < 64) {
    const float invp = invPs[t];
    float lg[48];
    float m = -3.4e38f;
#pragma unroll
    for (int j = 0; j < 48; ++j) {
      lg[j] = L[t][j] * invp * invTs[j] * kScale;
      m = fmaxf(m, lg[j]);
    }
    float s = 0.f;
#pragma unroll
    for (int j = 0; j < 48; ++j) {
      lg[j] = expf(lg[j] - m);
      s += lg[j];
    }
    const float is = 1.0f / s;
    float* ao = attnp + ((size_t)b * NP + pt * 64 + t) * NT;
    float* ro = rn + ((size_t)b * NP + pt * 64 + t) * NT;
#pragma unroll
    for (int j = 0; j < 48; ++j) ao[j] = lg[j] * is * invTs[j];
#pragma unroll
    for (int j = 0; j < 48; ++j) ro[j] = L[t][j] * invp;
  }
}

// ---------------------------------------------------------------------------
// K2: score[p][q] = sum_t attn'[p][t] * Rn[q][t], argmax over q folded in via
// packed (mono-float | ~q) atomicMax (order-independent -> deterministic).
// ---------------------------------------------------------------------------
__global__ __launch_bounds__(256) void k2_score_argmax(
    const float* __restrict__ attnp, const float* __restrict__ rn,
    unsigned long long* __restrict__ umax) {
  const int b = blockIdx.y;
  const int qt = blockIdx.x & 3;
  const int pb = blockIdx.x >> 2;
  const int t = threadIdx.x;
  const int tp = t >> 4, tq = t & 15;

  __shared__ float aS[48][68];
  __shared__ float rS[48][68];

  const float* ab = attnp + ((size_t)b * NP + pb * 64) * NT;
  const float* rb = rn + ((size_t)b * NP + qt * 64) * NT;
#pragma unroll
  for (int l = 0; l < 3; ++l) {
    int u = t + 256 * l;  // 64 rows x 12 f4
    int row = u / 12, c4 = u % 12;
    float4 v = *(const float4*)(ab + (size_t)row * NT + c4 * 4);
    aS[c4 * 4 + 0][row] = v.x;
    aS[c4 * 4 + 1][row] = v.y;
    aS[c4 * 4 + 2][row] = v.z;
    aS[c4 * 4 + 3][row] = v.w;
    float4 wv = *(const float4*)(rb + (size_t)row * NT + c4 * 4);
    rS[c4 * 4 + 0][row] = wv.x;
    rS[c4 * 4 + 1][row] = wv.y;
    rS[c4 * 4 + 2][row] = wv.z;
    rS[c4 * 4 + 3][row] = wv.w;
  }
  __syncthreads();

  float acc[4][4] = {};
#pragma unroll
  for (int k = 0; k < 48; ++k) {
    float4 av = *(const float4*)&aS[k][tp * 4];
    float4 rv = *(const float4*)&rS[k][tq * 4];
    float aa[4] = {av.x, av.y, av.z, av.w};
    float rr[4] = {rv.x, rv.y, rv.z, rv.w};
#pragma unroll
    for (int i = 0; i < 4; ++i)
#pragma unroll
      for (int j = 0; j < 4; ++j) acc[i][j] += aa[i] * rr[j];
  }

#pragma unroll
  for (int i = 0; i < 4; ++i) {
    float bs = acc[i][0];
    int bq = qt * 64 + tq * 4;
#pragma unroll
    for (int j = 1; j < 4; ++j) {
      float s = acc[i][j];
      int qq = qt * 64 + tq * 4 + j;
      if (s > bs) {  // strict > keeps smallest q on ties
        bs = s;
        bq = qq;
      }
    }
    unsigned us = __float_as_uint(bs);
    us = (us & 0x80000000u) ? ~us : (us | 0x80000000u);
    unsigned long long key =
        ((unsigned long long)us << 32) | (unsigned long long)(0xFFFFFFFFu - (unsigned)bq);
    for (int o = 8; o >= 1; o >>= 1) {
      unsigned long long ok = __shfl_xor(key, o, 16);
      if (ok > key) key = ok;
    }
    if (tq == 0) atomicMax(&umax[(size_t)b * NP + pb * 64 + tp * 4 + i], key);
  }
}

// ---------------------------------------------------------------------------
// K3: per batch: decode argmax, vote counts, exact rank (count desc, idx asc),
// keep rank<128, emit ascending; gather pos/mask in the same block.
// ---------------------------------------------------------------------------
__global__ __launch_bounds__(256) void k3_select_meta(
    const unsigned long long* __restrict__ umax, const int* __restrict__ pos,
    const int* __restrict__ msk, int* __restrict__ order,
    float* __restrict__ out1, float* __restrict__ out2) {
  const int b = blockIdx.x, t = threadIdx.x;
  __shared__ int cnt[256];
  __shared__ int kept[256];
  __shared__ int sorder[NKEEP];
  cnt[t] = 0;
  __syncthreads();
  unsigned long long key = umax[(size_t)b * NP + t];
  int q = (int)(0xFFFFFFFFu - (unsigned)(key & 0xFFFFFFFFull));
  atomicAdd(&cnt[q], 1);
  __syncthreads();
  const int c = cnt[t];
  int rank = 0;
  for (int u = 0; u < 256; ++u) {
    int cu = cnt[u];
    rank += (cu > c || (cu == c && u < t)) ? 1 : 0;
  }
  kept[t] = (rank < NKEEP) ? 1 : 0;
  __syncthreads();
  if (kept[t]) {
    int posn = 0;
    for (int u = 0; u < t; ++u) posn += kept[u];
    order[b * NKEEP + posn] = t;
    sorder[posn] = t;
  }
  __syncthreads();
  if (t < SOUT) {
    int src;
    if (t == 0) src = 0;
    else if (t < 1 + NKEEP) src = 1 + sorder[t - 1];
    else src = t + (NP - NKEEP);
    out1[b * SOUT + t] = (float)pos[b * SEQ + src];
    out2[b * SOUT + t] = (float)msk[b * SEQ + src];
  }
}

// ---------------------------------------------------------------------------
// K4: gather only the 128 kept patch rows (cls/task copied in k1a).
// ---------------------------------------------------------------------------
__global__ __launch_bounds__(256) void k4_gather_kept(
    const float* __restrict__ tokens, const int* __restrict__ order,
    float* __restrict__ out) {
  const int ki = blockIdx.x;  // 0..127
  const int b = blockIdx.y;
  const int t = threadIdx.x;
  const int src = 1 + order[b * NKEEP + ki];
  const float4* in4 = (const float4*)(tokens + ((size_t)b * SEQ + src) * DIM);
  float4* o4 = (float4*)(out + ((size_t)b * SOUT + 1 + ki) * DIM);
  o4[t] = in4[t];
  o4[t + 256] = in4[t + 256];
}

// ---------------------------------------------------------------------------
extern "C" void kernel_launch(void* const* d_in, const int* in_sizes, int n_in,
                              void* d_out, int out_size, void* d_ws,
                              size_t ws_size, hipStream_t stream) {
  const float* tokens = (const float*)d_in[0];
  const int* pos = (const int*)d_in[1];
  const int* msk = (const int*)d_in[2];

  float* out0 = (float*)d_out;
  float* out1 = out0 + (size_t)NB * SOUT * DIM;
  float* out2 = out1 + (size_t)NB * SOUT;

  // adaptive split-K depth by workspace size
  const size_t fixed = (size_t)(2 * NB * NP * NT) * 4 + (size_t)NB * NP * 8 +
                       (size_t)NB * NKEEP * 4;
  const size_t perndc = (size_t)NB * (NT * NP + NP + NT) * 4;
  int ndc = 16;
  while (ndc > 4 && fixed + (size_t)ndc * perndc > ws_size) ndc >>= 1;
  const int dchunk = DIM / ndc;

  char* ws = (char*)d_ws;
  float* attnp = (float*)ws;                 // NB*NP*NT
  float* rn = attnp + (size_t)NB * NP * NT;  // NB*NP*NT
  unsigned long long* umax = (unsigned long long*)(rn + (size_t)NB * NP * NT);
  int* order = (int*)(umax + (size_t)NB * NP);
  float* rpart = (float*)(order + (size_t)NB * NKEEP);  // NB*ndc*48*256
  float* ssqP = rpart + (size_t)NB * ndc * NT * NP;     // NB*ndc*256
  float* ssqT = ssqP + (size_t)NB * ndc * NP;           // NB*ndc*48

  k1a_partial_gemm<<<dim3(1 + ndc, NB), 256, 0, stream>>>(
      tokens, rpart, ssqP, ssqT, out0, ndc, dchunk);
  k1b_reduce_softmax<<<dim3(4, NB), 256, 0, stream>>>(rpart, ssqP, ssqT, attnp,
                                                      rn, umax, ndc);
  k2_score_argmax<<<dim3(16, NB), 256, 0, stream>>>(attnp, rn, umax);
  k3_select_meta<<<NB, 256, 0, stream>>>(umax, pos, msk, order, out1, out2);
  k4_gather_kept<<<dim3(NKEEP, NB), 256, 0, stream>>>(tokens, order, out0);
}

// Round 9
// 202.190 us; speedup vs baseline: 3.2549x; 3.2549x over previous
//
#include <hip/hip_runtime.h>

#define NB 64      // batch
#define SEQ 305    // sequence length
#define DIM 2048   // hidden
#define NP 256     // patches
#define NT 48      // task tokens
#define NKEEP 128  // kept patches
#define SOUT 177   // 1 + 128 + 48
#define KS 32      // d-depth per LDS stage

static_assert(1 + NP + NT == SEQ, "layout");

constexpr float kScale = 0.022097086912079608f;  // 1/sqrt(2048)

// ---------------------------------------------------------------------------
// K1a: grid (1 + 2*ndc, 64), 128 threads (2 waves). x==0: fused static copy
// (cls+task rows, 256 thr worth of work done by 128). Else: xi=x-1,
// dci=xi>>1, pt=xi&1. Tile 128p x 48t x dchunk, micro-tile 8x6 (R5-validated
// ratio and code shape). LDS [d][row] stride 140 (16B-aligned; reads 2-way =
// free, staging writes 4-way = known ~11 us cost). 128 thr: pg=t>>3 (0..15),
// tg=t&7. Staging st[11]: u=t+128l; l=0..7 p rows (1024 f4), l=8..10 t rows
// (384 f4) -- exact loop-bound fit, branches resolve per l.
// ssq fused into staging, shfl-reduced over the 8 lanes of a row group.
// ---------------------------------------------------------------------------
__global__ __launch_bounds__(128) void k1a_partial_gemm(
    const float* __restrict__ tokens, float* __restrict__ rpart,
    float* __restrict__ ssqP, float* __restrict__ ssqT,
    float* __restrict__ out0, int ndc, int dchunk) {
  const int b = blockIdx.y;
  const int t = threadIdx.x;

  if (blockIdx.x == 0) {
    // copy cls (row 0 -> 0) and task rows (257..304 -> 129..176)
#pragma unroll 2
    for (int l = 0; l < 196; ++l) {
      int u = l * 128 + t;  // 49 rows * 512 f4
      int row = u >> 9, c = u & 511;
      int srow = (row == 0) ? 0 : (256 + row);
      int drow = (row == 0) ? 0 : (128 + row);
      *(float4*)(out0 + ((size_t)b * SOUT + drow) * DIM + (size_t)c * 4) =
          *(const float4*)(tokens + ((size_t)b * SEQ + srow) * DIM + (size_t)c * 4);
    }
    return;
  }

  const int xi = blockIdx.x - 1;
  const int dci = xi >> 1;
  const int pt = xi & 1;
  const int pg = t >> 3;  // 0..15: p-rows pg*8..pg*8+7 (of this 128-half)
  const int tg = t & 7;   // 0..7:  t-cols tg*6..tg*6+5

  __shared__ __align__(16) float pC[KS][140];  // [d][p-row], stride 140
  __shared__ __align__(16) float tC[KS][64];   // [d][t-slot]: row r at (r/6)*8+r%6

  const float* pbase =
      tokens + ((size_t)b * SEQ + 1 + pt * 128) * DIM + (size_t)dci * dchunk;
  const float* tbase =
      tokens + ((size_t)b * SEQ + 1 + NP) * DIM + (size_t)dci * dchunk;

  float4 st[11];
  float acc[8][6] = {};
  float ssqa[11] = {};
  const int nchunk = dchunk / KS;

  // staging map: u = t + 128*l. l=0..7: p (row=u>>3 in 0..127, c8=u&7);
  // l=8..10: t (v=u-1024: row=v>>3 in 0..47, c8=v&7).
  auto gload = [&](int ck) {
#pragma unroll
    for (int l = 0; l < 11; ++l) {
      int u = t + 128 * l;
      if (u < 1024) {
        int row = u >> 3, c8 = u & 7;
        st[l] = *(const float4*)(pbase + (size_t)row * DIM + ck * KS + c8 * 4);
      } else {
        int v = u - 1024;
        int row = v >> 3, c8 = v & 7;
        st[l] = *(const float4*)(tbase + (size_t)row * DIM + ck * KS + c8 * 4);
      }
    }
  };
  auto lwrite = [&]() {
#pragma unroll
    for (int l = 0; l < 11; ++l) {
      int u = t + 128 * l;
      float4 v = st[l];
      if (u < 1024) {
        int row = u >> 3, c8 = u & 7;
        pC[c8 * 4 + 0][row] = v.x;
        pC[c8 * 4 + 1][row] = v.y;
        pC[c8 * 4 + 2][row] = v.z;
        pC[c8 * 4 + 3][row] = v.w;
        ssqa[l] += v.x * v.x + v.y * v.y + v.z * v.z + v.w * v.w;
      } else {
        int vv = u - 1024;
        int row = vv >> 3, c8 = vv & 7;
        int slot = (row / 6) * 8 + (row % 6);
        tC[c8 * 4 + 0][slot] = v.x;
        tC[c8 * 4 + 1][slot] = v.y;
        tC[c8 * 4 + 2][slot] = v.z;
        tC[c8 * 4 + 3][slot] = v.w;
        ssqa[l] += v.x * v.x + v.y * v.y + v.z * v.z + v.w * v.w;
      }
    }
  };

  gload(0);
  for (int ck = 0; ck < nchunk; ++ck) {
    __syncthreads();  // previous compute done reading LDS
    lwrite();
    if (ck + 1 < nchunk) gload(ck + 1);  // prefetch overlaps compute below
    __syncthreads();
#pragma unroll 4
    for (int dd = 0; dd < KS; ++dd) {
      float4 p0 = *(const float4*)&pC[dd][pg * 8];
      float4 p1 = *(const float4*)&pC[dd][pg * 8 + 4];
      float4 t0 = *(const float4*)&tC[dd][tg * 8];
      float2 t1 = *(const float2*)&tC[dd][tg * 8 + 4];
      float pa[8] = {p0.x, p0.y, p0.z, p0.w, p1.x, p1.y, p1.z, p1.w};
      float tb[6] = {t0.x, t0.y, t0.z, t0.w, t1.x, t1.y};
#pragma unroll
      for (int i = 0; i < 8; ++i)
#pragma unroll
        for (int j = 0; j < 6; ++j) acc[i][j] += pa[i] * tb[j];
    }
  }

  // partial R, transposed: rpart[(b*ndc+dci)][jg][256], cols pt*128+pg*8
  float* rp = rpart + ((size_t)b * ndc + dci) * (NT * NP) + pt * 128;
#pragma unroll
  for (int j = 0; j < 6; ++j) {
    int jg = tg * 6 + j;
    float4 v0 = {acc[0][j], acc[1][j], acc[2][j], acc[3][j]};
    float4 v1 = {acc[4][j], acc[5][j], acc[6][j], acc[7][j]};
    *(float4*)(rp + jg * NP + pg * 8) = v0;
    *(float4*)(rp + jg * NP + pg * 8 + 4) = v1;
  }

  // ssq: reduce across the 8 staging lanes of each row (fixed order)
#pragma unroll
  for (int l = 0; l < 11; ++l) {
    float s = ssqa[l];
    s += __shfl_down(s, 4, 8);
    s += __shfl_down(s, 2, 8);
    s += __shfl_down(s, 1, 8);
    ssqa[l] = s;
  }
  if ((t & 7) == 0) {
#pragma unroll
    for (int l = 0; l < 11; ++l) {
      int u = t + 128 * l;
      if (u < 1024) {
        ssqP[((size_t)b * ndc + dci) * NP + pt * 128 + (u >> 3)] = ssqa[l];
      } else {
        if (pt == 0)
          ssqT[((size_t)b * ndc + dci) * NT + ((u - 1024) >> 3)] = ssqa[l];
      }
    }
  }
}

// ---------------------------------------------------------------------------
// K1b: grid (4 pt, 64 b), 256 thr. Sum ndc partials in fixed order
// (deterministic), rms + softmax, write attnp = softmax*invT and
// rn = raw*invP. Inits umax.
// ---------------------------------------------------------------------------
__global__ __launch_bounds__(256) void k1b_reduce_softmax(
    const float* __restrict__ rpart, const float* __restrict__ ssqP,
    const float* __restrict__ ssqT, float* __restrict__ attnp,
    float* __restrict__ rn, unsigned long long* __restrict__ umax, int ndc) {
  const int pt = blockIdx.x;
  const int b = blockIdx.y;
  const int t = threadIdx.x;
  const int r = t & 63;
  const int q = t >> 6;

  __shared__ float L[64][49];
  __shared__ float invPs[64];
  __shared__ float invTs[48];

  float a[12] = {};
  const float* rb = rpart + (size_t)b * ndc * (NT * NP) + pt * 64 + r;
  for (int dci = 0; dci < ndc; ++dci) {
    const float* rp = rb + (size_t)dci * (NT * NP);
#pragma unroll
    for (int j = 0; j < 12; ++j) a[j] += rp[(q * 12 + j) * NP];
  }
#pragma unroll
  for (int j = 0; j < 12; ++j) L[r][q * 12 + j] = a[j];

  if (t < 64) {
    float s = 0.f;
    for (int dci = 0; dci < ndc; ++dci)
      s += ssqP[((size_t)b * ndc + dci) * NP + pt * 64 + t];
    invPs[t] = 1.0f / sqrtf(s * (1.0f / 2048.0f) + 1e-6f);
    umax[(size_t)b * NP + pt * 64 + t] = 0ull;
  } else if (t < 112) {
    int j = t - 64;
    float s = 0.f;
    for (int dci = 0; dci < ndc; ++dci)
      s += ssqT[((size_t)b * ndc + dci) * NT + j];
    invTs[j] = 1.0f / sqrtf(s * (1.0f / 2048.0f) + 1e-6f);
  }
  __syncthreads();

  if (t < 64) {
    const float invp = invPs[t];
    float lg[48];
    float m = -3.4e38f;
#pragma unroll
    for (int j = 0; j < 48; ++j) {
      lg[j] = L[t][j] * invp * invTs[j] * kScale;
      m = fmaxf(m, lg[j]);
    }
    float s = 0.f;
#pragma unroll
    for (int j = 0; j < 48; ++j) {
      lg[j] = expf(lg[j] - m);
      s += lg[j];
    }
    const float is = 1.0f / s;
    float* ao = attnp + ((size_t)b * NP + pt * 64 + t) * NT;
    float* ro = rn + ((size_t)b * NP + pt * 64 + t) * NT;
#pragma unroll
    for (int j = 0; j < 48; ++j) ao[j] = lg[j] * is * invTs[j];
#pragma unroll
    for (int j = 0; j < 48; ++j) ro[j] = L[t][j] * invp;
  }
}

// ---------------------------------------------------------------------------
// K2: score[p][q] = sum_t attn'[p][t] * Rn[q][t], argmax over q folded in via
// packed (mono-float | ~q) atomicMax (order-independent -> deterministic).
// ---------------------------------------------------------------------------
__global__ __launch_bounds__(256) void k2_score_argmax(
    const float* __restrict__ attnp, const float* __restrict__ rn,
    unsigned long long* __restrict__ umax) {
  const int b = blockIdx.y;
  const int qt = blockIdx.x & 3;
  const int pb = blockIdx.x >> 2;
  const int t = threadIdx.x;
  const int tp = t >> 4, tq = t & 15;

  __shared__ float aS[48][68];
  __shared__ float rS[48][68];

  const float* ab = attnp + ((size_t)b * NP + pb * 64) * NT;
  const float* rb = rn + ((size_t)b * NP + qt * 64) * NT;
#pragma unroll
  for (int l = 0; l < 3; ++l) {
    int u = t + 256 * l;  // 64 rows x 12 f4
    int row = u / 12, c4 = u % 12;
    float4 v = *(const float4*)(ab + (size_t)row * NT + c4 * 4);
    aS[c4 * 4 + 0][row] = v.x;
    aS[c4 * 4 + 1][row] = v.y;
    aS[c4 * 4 + 2][row] = v.z;
    aS[c4 * 4 + 3][row] = v.w;
    float4 wv = *(const float4*)(rb + (size_t)row * NT + c4 * 4);
    rS[c4 * 4 + 0][row] = wv.x;
    rS[c4 * 4 + 1][row] = wv.y;
    rS[c4 * 4 + 2][row] = wv.z;
    rS[c4 * 4 + 3][row] = wv.w;
  }
  __syncthreads();

  float acc[4][4] = {};
#pragma unroll
  for (int k = 0; k < 48; ++k) {
    float4 av = *(const float4*)&aS[k][tp * 4];
    float4 rv = *(const float4*)&rS[k][tq * 4];
    float aa[4] = {av.x, av.y, av.z, av.w};
    float rr[4] = {rv.x, rv.y, rv.z, rv.w};
#pragma unroll
    for (int i = 0; i < 4; ++i)
#pragma unroll
      for (int j = 0; j < 4; ++j) acc[i][j] += aa[i] * rr[j];
  }

#pragma unroll
  for (int i = 0; i < 4; ++i) {
    float bs = acc[i][0];
    int bq = qt * 64 + tq * 4;
#pragma unroll
    for (int j = 1; j < 4; ++j) {
      float s = acc[i][j];
      int qq = qt * 64 + tq * 4 + j;
      if (s > bs) {  // strict > keeps smallest q on ties
        bs = s;
        bq = qq;
      }
    }
    unsigned us = __float_as_uint(bs);
    us = (us & 0x80000000u) ? ~us : (us | 0x80000000u);
    unsigned long long key =
        ((unsigned long long)us << 32) | (unsigned long long)(0xFFFFFFFFu - (unsigned)bq);
    for (int o = 8; o >= 1; o >>= 1) {
      unsigned long long ok = __shfl_xor(key, o, 16);
      if (ok > key) key = ok;
    }
    if (tq == 0) atomicMax(&umax[(size_t)b * NP + pb * 64 + tp * 4 + i], key);
  }
}

// ---------------------------------------------------------------------------
// K3: per batch: decode argmax, vote counts, exact rank (count desc, idx asc),
// keep rank<128, emit ascending; gather pos/mask in the same block.
// ---------------------------------------------------------------------------
__global__ __launch_bounds__(256) void k3_select_meta(
    const unsigned long long* __restrict__ umax, const int* __restrict__ pos,
    const int* __restrict__ msk, int* __restrict__ order,
    float* __restrict__ out1, float* __restrict__ out2) {
  const int b = blockIdx.x, t = threadIdx.x;
  __shared__ int cnt[256];
  __shared__ int kept[256];
  __shared__ int sorder[NKEEP];
  cnt[t] = 0;
  __syncthreads();
  unsigned long long key = umax[(size_t)b * NP + t];
  int q = (int)(0xFFFFFFFFu - (unsigned)(key & 0xFFFFFFFFull));
  atomicAdd(&cnt[q], 1);
  __syncthreads();
  const int c = cnt[t];
  int rank = 0;
  for (int u = 0; u < 256; ++u) {
    int cu = cnt[u];
    rank += (cu > c || (cu == c && u < t)) ? 1 : 0;
  }
  kept[t] = (rank < NKEEP) ? 1 : 0;
  __syncthreads();
  if (kept[t]) {
    int posn = 0;
    for (int u = 0; u < t; ++u) posn += kept[u];
    order[b * NKEEP + posn] = t;
    sorder[posn] = t;
  }
  __syncthreads();
  if (t < SOUT) {
    int src;
    if (t == 0) src = 0;
    else if (t < 1 + NKEEP) src = 1 + sorder[t - 1];
    else src = t + (NP - NKEEP);
    out1[b * SOUT + t] = (float)pos[b * SEQ + src];
    out2[b * SOUT + t] = (float)msk[b * SEQ + src];
  }
}

// ---------------------------------------------------------------------------
// K4: gather only the 128 kept patch rows (cls/task copied in k1a).
// ---------------------------------------------------------------------------
__global__ __launch_bounds__(256) void k4_gather_kept(
    const float* __restrict__ tokens, const int* __restrict__ order,
    float* __restrict__ out) {
  const int ki = blockIdx.x;  // 0..127
  const int b = blockIdx.y;
  const int t = threadIdx.x;
  const int src = 1 + order[b * NKEEP + ki];
  const float4* in4 = (const float4*)(tokens + ((size_t)b * SEQ + src) * DIM);
  float4* o4 = (float4*)(out + ((size_t)b * SOUT + 1 + ki) * DIM);
  o4[t] = in4[t];
  o4[t + 256] = in4[t + 256];
}

// ---------------------------------------------------------------------------
extern "C" void kernel_launch(void* const* d_in, const int* in_sizes, int n_in,
                              void* d_out, int out_size, void* d_ws,
                              size_t ws_size, hipStream_t stream) {
  const float* tokens = (const float*)d_in[0];
  const int* pos = (const int*)d_in[1];
  const int* msk = (const int*)d_in[2];

  float* out0 = (float*)d_out;
  float* out1 = out0 + (size_t)NB * SOUT * DIM;
  float* out2 = out1 + (size_t)NB * SOUT;

  // adaptive split-K depth by workspace size
  const size_t fixed = (size_t)(2 * NB * NP * NT) * 4 + (size_t)NB * NP * 8 +
                       (size_t)NB * NKEEP * 4;
  const size_t perndc = (size_t)NB * (NT * NP + NP + NT) * 4;
  int ndc = 16;
  while (ndc > 4 && fixed + (size_t)ndc * perndc > ws_size) ndc >>= 1;
  const int dchunk = DIM / ndc;

  char* ws = (char*)d_ws;
  float* attnp = (float*)ws;                 // NB*NP*NT
  float* rn = attnp + (size_t)NB * NP * NT;  // NB*NP*NT
  unsigned long long* umax = (unsigned long long*)(rn + (size_t)NB * NP * NT);
  int* order = (int*)(umax + (size_t)NB * NP);
  float* rpart = (float*)(order + (size_t)NB * NKEEP);  // NB*ndc*48*256
  float* ssqP = rpart + (size_t)NB * ndc * NT * NP;     // NB*ndc*256
  float* ssqT = ssqP + (size_t)NB * ndc * NP;           // NB*ndc*48

  k1a_partial_gemm<<<dim3(1 + 2 * ndc, NB), 128, 0, stream>>>(
      tokens, rpart, ssqP, ssqT, out0, ndc, dchunk);
  k1b_reduce_softmax<<<dim3(4, NB), 256, 0, stream>>>(rpart, ssqP, ssqT, attnp,
                                                      rn, umax, ndc);
  k2_score_argmax<<<dim3(16, NB), 256, 0, stream>>>(attnp, rn, umax);
  k3_select_meta<<<NB, 256, 0, stream>>>(umax, pos, msk, order, out1, out2);
  k4_gather_kept<<<dim3(NKEEP, NB), 256, 0, stream>>>(tokens, order, out0);
}